// Round 17
// baseline (50.240 us; speedup 1.0000x reference)
//
#include <hip/hip_runtime.h>

// SSIM loss, 7x7 window, VALID, (64,1,512,512) fp32.
// R17 = R16 with the h2 type fixed to __fp16 ext_vector (cvt_pkrtz's return
// type; also matches fdot2's V2h signature). f16-packed LDS staging +
// v_dot2_f32_f16 tap math:
// - stage {x,y} as one packed-f16 dword (cvt_pkrtz): LDS data halved
// - per tap: fdot2(t,t) = x^2+y^2 (1 inst); fdot2(t,swap(t)) = 2xy
// - {hx,hy} via packed f16 adds, then 2 cvt to f32
// - 4 vertical channels (ss folded, w=2*Sxy; t2 = 49*vw - 2*p1 + c2s)

constexpr int B  = 64;
constexpr int H  = 512, W = 512;
constexpr int OH = H - 6, OW = W - 6;     // 506
constexpr int CW = 64;                    // cols per wave
constexpr int BW_ = 4 * CW;               // cols per block
constexpr int SH = 32;                    // output rows per block

typedef __fp16 h2 __attribute__((ext_vector_type(2)));

__global__ __launch_bounds__(256)
void ssim_main(const float* __restrict__ X, const float* __restrict__ Y,
               const float* __restrict__ DR, float* __restrict__ partials)
{
    const int tid  = threadIdx.x;
    const int wid  = tid >> 6;
    const int lane = tid & 63;
    const int c0   = blockIdx.x * BW_ + wid * CW;   // wave-private strip
    const int r0   = blockIdx.y * SH;
    const int b    = blockIdx.z;

    const int out_rows = min(SH, OH - r0);
    const int rows_in  = out_rows + 6;       // <= 38, block-uniform

    const float d  = DR[b];
    const float C1 = (0.01f * d) * (0.01f * d);
    const float C2 = (0.03f * d) * (0.03f * d);
    const float c1s = 2401.0f * C1;          // 49^2 * C1
    const float c2s = 2352.0f * C2;          // 48*49 * C2

    const float* __restrict__ Xb = X + (size_t)b * H * W;
    const float* __restrict__ Yb = Y + (size_t)b * H * W;

    unsigned off  = (unsigned)(r0 * W + c0 + lane);
    unsigned hoff = (unsigned)(r0 * W + min(c0 + CW + lane, W - 1));

    const bool colvalid = (c0 + lane) < OW;
    const bool is_halo  = lane < 6;

    // wave-private row buffer: packed f16 {x,y} per col, 70 used
    __shared__ h2 rbu[4][CW + 8];
    h2* const buf = rbu[wid];

    // vertical state: 4 channels {sx, sy, ss=Sxx+Syy, w=2*Sxy}, 7-row history
    float bhx[7], bhy[7], bhs[7], bhw[7];
    float vx = 0.f, vy = 0.f, vss = 0.f, vw = 0.f;
#pragma unroll
    for (int i = 0; i < 7; ++i) { bhx[i]=bhy[i]=bhs[i]=bhw[i]=0.f; }

    float acc = 0.f;

    // depth-2 prefetch (f32 pairs; converted at stage time)
    float2 pre0, pre1;
    float2 preh0 = make_float2(0.f,0.f), preh1 = make_float2(0.f,0.f);
    pre0.x = Xb[off]; pre0.y = Yb[off];
    if (is_halo) { preh0.x = Xb[hoff]; preh0.y = Yb[hoff]; }
    off += W; hoff += W;
    pre1.x = Xb[off]; pre1.y = Yb[off];
    if (is_halo) { preh1.x = Xb[hoff]; preh1.y = Yb[hoff]; }
    off += W; hoff += W;

    for (int rr = 0; rr < 42; rr += 14) {
#pragma unroll
        for (int p = 0; p < 14; ++p) {
            const int r = rr + p;              // r%7 == p%7, r&1 == p&1
            if (r < rows_in) {                 // block-uniform
                float2& pr = (p & 1) ? pre1 : pre0;
                float2& ph = (p & 1) ? preh1 : preh0;
                buf[lane] = __builtin_amdgcn_cvt_pkrtz(pr.x, pr.y);
                if (is_halo) buf[CW + lane] = __builtin_amdgcn_cvt_pkrtz(ph.x, ph.y);
                // no barrier: wave-private region, DS ops in-order per wave

                // issue row r+2's loads; latency hides under compute
                if (r + 2 < rows_in) {
                    pr.x = Xb[off]; pr.y = Yb[off];
                    if (is_halo) { ph.x = Xb[hoff]; ph.y = Yb[hoff]; }
                    off += W; hoff += W;
                }

                // 7 packed taps
                const h2 t0 = buf[lane+0], t1 = buf[lane+1], t2_ = buf[lane+2],
                         t3 = buf[lane+3], t4 = buf[lane+4], t5 = buf[lane+5],
                         t6 = buf[lane+6];

                // hss = sum(x^2+y^2): one fdot2 per tap
                float hss = __builtin_amdgcn_fdot2(t0, t0, 0.f, false);
                hss = __builtin_amdgcn_fdot2(t1, t1, hss, false);
                hss = __builtin_amdgcn_fdot2(t2_, t2_, hss, false);
                hss = __builtin_amdgcn_fdot2(t3, t3, hss, false);
                hss = __builtin_amdgcn_fdot2(t4, t4, hss, false);
                hss = __builtin_amdgcn_fdot2(t5, t5, hss, false);
                hss = __builtin_amdgcn_fdot2(t6, t6, hss, false);

                // hw = 2*sum(x*y): fdot2(t, swap(t))
                #define SW(t) __builtin_shufflevector(t, t, 1, 0)
                float hw = __builtin_amdgcn_fdot2(t0, SW(t0), 0.f, false);
                hw = __builtin_amdgcn_fdot2(t1, SW(t1), hw, false);
                hw = __builtin_amdgcn_fdot2(t2_, SW(t2_), hw, false);
                hw = __builtin_amdgcn_fdot2(t3, SW(t3), hw, false);
                hw = __builtin_amdgcn_fdot2(t4, SW(t4), hw, false);
                hw = __builtin_amdgcn_fdot2(t5, SW(t5), hw, false);
                hw = __builtin_amdgcn_fdot2(t6, SW(t6), hw, false);
                #undef SW

                // {hx,hy} via packed f16 adds
                const h2 hp = ((t0 + t1) + (t2_ + t3)) + ((t4 + t5) + t6);
                const float hx = (float)hp.x;
                const float hy = (float)hp.y;

                // vertical running 7-row window (slot p%7 holds row r-7)
                constexpr int s7[14] = {0,1,2,3,4,5,6,0,1,2,3,4,5,6};
                const int sp = s7[p];
                vx  += hx  - bhx[sp]; bhx[sp] = hx;
                vy  += hy  - bhy[sp]; bhy[sp] = hy;
                vss += hss - bhs[sp]; bhs[sp] = hss;
                vw  += hw  - bhw[sp]; bhw[sp] = hw;

                if (r >= 6 && colvalid) {
                    // S = (2 SxSy + c1s)(49*vw - 2 SxSy + c2s)
                    //   / (Sx^2+Sy^2+c1s)(49*vss - Sx^2 - Sy^2 + c2s)
                    const float p1 = vx * vy;
                    const float t1f = fmaf(2.f, p1, c1s);
                    const float t2f = fmaf(-2.f, p1, fmaf(49.f, vw, c2s));
                    const float n2 = fmaf(vy, vy, vx * vx);
                    const float b1 = n2 + c1s;
                    const float b2 = fmaf(49.f, vss, c2s) - n2;
                    const float den = b1 * b2;
                    float rc = __builtin_amdgcn_rcpf(den);
                    rc = rc * (2.f - den * rc);          // 1 Newton step
                    acc = fmaf(t1f * t2f, rc, acc);
                }
            }
        }
    }

    // block reduction: wave shfl, then cross-wave via LDS (single barrier)
    float s = acc;
#pragma unroll
    for (int o = 32; o; o >>= 1) s += __shfl_down(s, o, 64);
    __shared__ float wsum[4];
    if (lane == 0) wsum[wid] = s;
    __syncthreads();
    if (tid == 0) {
        const int bid = (blockIdx.z * gridDim.y + blockIdx.y) * gridDim.x + blockIdx.x;
        partials[bid] = wsum[0] + wsum[1] + wsum[2] + wsum[3];
    }
}

__global__ __launch_bounds__(256)
void ssim_final(const float* __restrict__ partials, int n,
                float* __restrict__ out, float inv_count)
{
    const int tid = threadIdx.x;
    float s = 0.f;
    for (int i = tid; i < n; i += 256) s += partials[i];
#pragma unroll
    for (int o = 32; o; o >>= 1) s += __shfl_down(s, o, 64);
    __shared__ float wsum[4];
    if ((tid & 63) == 0) wsum[tid >> 6] = s;
    __syncthreads();
    if (tid == 0) out[0] = 1.0f - (wsum[0] + wsum[1] + wsum[2] + wsum[3]) * inv_count;
}

extern "C" void kernel_launch(void* const* d_in, const int* in_sizes, int n_in,
                              void* d_out, int out_size, void* d_ws, size_t ws_size,
                              hipStream_t stream)
{
    const float* X  = (const float*)d_in[0];
    const float* Y  = (const float*)d_in[1];
    const float* DR = (const float*)d_in[2];
    float* out      = (float*)d_out;
    float* partials = (float*)d_ws;

    const int gx = (OW + BW_ - 1) / BW_; // 2
    const int gy = (OH + SH - 1) / SH;   // 16
    dim3 grid(gx, gy, B);                // 2048 blocks, every partial slot written
    ssim_main<<<grid, 256, 0, stream>>>(X, Y, DR, partials);

    const int n = gx * gy * B;           // 2048
    const float inv_count = 1.0f / (float)((long)B * OH * OW);
    ssim_final<<<1, 256, 0, stream>>>(partials, n, out, inv_count);
}